// Round 11
// baseline (23.538 us; speedup 1.0000x reference)
//
#include <hip/hip_runtime.h>
#include <math.h>

#define H_DIM 1024
#define N_DIM 64
#define BH 16          // h per block (4 waves x 4 h)
#define BL 128         // l per block
#define KL 8           // l per thread (stride 16)
#define NB 16          // n per batch
#define NBATCH (N_DIM / NB)   // 4

__device__ __forceinline__ float2 cmul(float2 a, float2 b) {
    return make_float2(fmaf(a.x, b.x, -(a.y * b.y)),
                       fmaf(a.x, b.y,   a.y * b.x));
}

// ---------------- wave-local exchange: zero main-loop barriers ----------------
// Wave owns 4 h. Build role: lane -> (nb=lane>>2, hb=lane&3), writes row `lane`
// (16 float2 pairs, pair j at pos j^nb). Consume role: lane -> (c=lane>>2,
// hc=lane&3), reads row 4*nl+hc at pos c^nl. Same-wave DS ordering makes the
// write->read dependence barrier-free.

__global__ __launch_bounds__(256, 4) void dss_wloc(
    const float* __restrict__ log_dt,   // (H,2)
    const float* __restrict__ llnr,     // (N,)
    const float* __restrict__ limv,     // (N,)
    const float* __restrict__ W,        // (H,N,2)
    const int*   __restrict__ Lp,
    float* __restrict__ out)            // (L,H)
{
    __shared__ float2 tbl[4][64 * 16];   // 32 KB: per-wave table
    __shared__ float2 pqw[4][NBATCH * 64]; // 8 KB: per-wave pq, all batches

    const int tid  = threadIdx.x;
    const int w    = tid >> 6;
    const int lane = tid & 63;
    const int h0   = blockIdx.x * BH;
    const int g    = blockIdx.y;         // l-segment (0..15)
    const int l0   = g * BL;
    const int L    = *Lp;

    const int hb = lane & 3, nb = lane >> 2;   // build role
    const int hc = lane & 3, c  = lane >> 2;   // consume role
    const int hw = h0 + w * 4;

    float2* mytbl = tbl[w];
    float2* mypq  = pqw[w];

    // ---- per-lane param build (NBATCH sets), all in registers ----
    const float dt0 = expf(log_dt[2 * (hw + hb)]);
    const float dt1 = expf(log_dt[2 * (hw + hb) + 1]);

    float2 sv[NBATCH], s16v[NBATCH], w0v[NBATCH];
    #pragma unroll
    for (int bt = 0; bt < NBATCH; ++bt) {
        const int n = bt * NB + nb;
        const float lre = -expf(llnr[n]);
        const float lmi = limv[n];
        const float a = dt0 * lre;
        const float b = dt1 * lmi;
        float sb, cbv;
        sincosf(b, &sb, &cbv);
        const float eA = expf(a);
        const float2 s = make_float2(eA * cbv, eA * sb);  // exp(dt_Lambda)
        sv[bt] = s;

        // Wk = Wc * (exp(dtL)-1) * conj(Lam)/max(|Lam|^2, eps^2)
        const float den = fmaxf(lre * lre + lmi * lmi, 1e-14f);
        const float rr = lre / den, ri = -lmi / den;
        const float em1r = s.x - 1.0f, em1i = s.y;
        const float2 wc = ((const float2*)W)[(size_t)(hw + hb) * N_DIM + n];
        const float tr = em1r * rr - em1i * ri;
        const float ti = em1r * ri + em1i * rr;
        const float2 wk = make_float2(wc.x * tr - wc.y * ti,
                                      wc.x * ti + wc.y * tr);

        const float2 s2 = cmul(s, s), s4 = cmul(s2, s2);
        const float2 s8 = cmul(s4, s4), s16 = cmul(s8, s8);
        s16v[bt] = s16;
        mypq[bt * 64 + lane] =
            make_float2(2.0f * s16.x, -(fmaf(s16.x, s16.x, s16.y * s16.y)));

        // w0 = wk * (s^128)^g, g <= 15: 4-bit square-multiply
        const float2 s32 = cmul(s16, s16), s64 = cmul(s32, s32);
        const float2 s128  = cmul(s64, s64);
        const float2 s256  = cmul(s128, s128);
        const float2 s512  = cmul(s256, s256);
        const float2 s1024 = cmul(s512, s512);
        float2 z = wk;
        if (g & 1) z = cmul(z, s128);
        if (g & 2) z = cmul(z, s256);
        if (g & 4) z = cmul(z, s512);
        if (g & 8) z = cmul(z, s1024);
        w0v[bt] = z;
    }

    float acc[KL];
    #pragma unroll
    for (int k = 0; k < KL; ++k) acc[k] = 0.0f;

    #pragma unroll
    for (int bt = 0; bt < NBATCH; ++bt) {
        // ---- build: dual 16-step chains, pair written as produced ----
        {
            const float2 w0 = w0v[bt], s = sv[bt];
            const float p1 = 2.0f * s.x;
            const float q1 = -(fmaf(s.x, s.x, s.y * s.y));
            const float2 w16 = cmul(w0, s16v[bt]);       // wk * s^(l0+16)

            float2* row = mytbl + lane * 16;
            float pa = w0.x;                              // t(l0)
            float ca = fmaf(w0.x, s.x, -(w0.y * s.y));    // t(l0+1)
            float pb = w16.x;                             // t(l0+16)
            float cb2 = fmaf(w16.x, s.x, -(w16.y * s.y)); // t(l0+17)
            row[0 ^ nb] = make_float2(pa, pb);
            row[1 ^ nb] = make_float2(ca, cb2);
            #pragma unroll
            for (int j = 2; j < 16; ++j) {
                const float na  = fmaf(p1, ca,  q1 * pa);
                const float nbv = fmaf(p1, cb2, q1 * pb);
                row[j ^ nb] = make_float2(na, nbv);
                pa = ca; ca = na; pb = cb2; cb2 = nbv;
            }
        }
        // no barrier: same-wave DS ordering guarantees visibility

        // ---- consume: one ds_read_b64 per n gives (ta, tb) seed ----
        const float2* pqb = mypq + bt * 64;
        #pragma unroll
        for (int nl = 0; nl < NB; ++nl) {
            const int r = 4 * nl + hc;
            const float2 tab = mytbl[r * 16 + (c ^ nl)];
            const float2 pq  = pqb[r];
            float ta = tab.x, tbv = tab.y;
            acc[0] += ta;
            acc[1] += tbv;
            #pragma unroll
            for (int k = 2; k < KL; ++k) {
                const float tc = fmaf(pq.x, tbv, pq.y * ta);
                acc[k] += tc;
                ta = tbv; tbv = tc;
            }
        }
    }

    // ---- epilogue: block LDS transpose (padded rows) -> float4 stores ----
    __syncthreads();                         // all waves done with their tables
    float* scr = (float*)(&tbl[0][0]);       // [128 l][20 floats] = 10 KB
    #pragma unroll
    for (int k = 0; k < KL; ++k)
        scr[(c + 16 * k) * 20 + 4 * w + hc] = acc[k];
    __syncthreads();
    const float4* scr4 = (const float4*)scr;
    float4* out4 = (float4*)out;
    #pragma unroll
    for (int i = 0; i < 2; ++i) {
        const int flat = i * 256 + tid;      // 128 l x 4 quads
        const int ll = flat >> 2, q = flat & 3;
        const int l = l0 + ll;
        if (l < L) out4[(size_t)l * (H_DIM / 4) + (h0 >> 2) + q] = scr4[ll * 5 + q];
    }
}

// ---------------- generic fallback (round-1 proven structure) ----------------

#define HT 64
#define CHUNK 16

__global__ __launch_bounds__(256) void dss_kernel_fb(
    const float* __restrict__ log_dt,
    const float* __restrict__ lam_log_neg_re,
    const float* __restrict__ lam_im,
    const float* __restrict__ W,
    const int*   __restrict__ Lp,
    float* __restrict__ out,
    int H, int N)
{
    __shared__ float4 params[N_DIM * HT];
    const int tid = threadIdx.x;
    const int h0 = blockIdx.x * HT;
    const int l0_blk = blockIdx.y * 64;
    const int L = *Lp;
    const float2* __restrict__ W2 = (const float2*)W;

    for (int flat = tid; flat < N * HT; flat += 256) {
        const int hl = flat & (HT - 1);
        const int n  = flat >> 6;
        const int h  = h0 + hl;
        const float dt0 = expf(log_dt[2 * h]);
        const float dt1 = expf(log_dt[2 * h + 1]);
        const float lre = -expf(lam_log_neg_re[n]);
        const float lmi = lam_im[n];
        const float a = dt0 * lre;
        const float b = dt1 * lmi;
        const float eA = expf(a);
        float sb, cb;
        sincosf(b, &sb, &cb);
        const float em1r = eA * cb - 1.0f;
        const float em1i = eA * sb;
        const float den = fmaxf(lre * lre + lmi * lmi, 1e-14f);
        const float rr =  lre / den;
        const float ri = -lmi / den;
        const float2 wc = W2[h * N + n];
        const float trm = em1r * rr - em1i * ri;
        const float tim = em1r * ri + em1i * rr;
        params[flat] = make_float4(a, b,
                                   wc.x * trm - wc.y * tim,
                                   wc.x * tim + wc.y * trm);
    }
    __syncthreads();

    const int hl = tid & (HT - 1);
    const int chunk = tid >> 6;
    const int l0 = l0_blk + chunk * CHUNK;
    if (l0 >= L) return;

    float acc[CHUNK];
    #pragma unroll
    for (int k = 0; k < CHUNK; ++k) acc[k] = 0.0f;

    const double TWO_PI  = 6.283185307179586476925286766559;
    const double INV_2PI = 0.15915494309189533576888376337251;

    for (int n = 0; n < N; ++n) {
        const float4 pp = params[n * HT + hl];
        const float a = pp.x, b = pp.y, wr = pp.z, wi = pp.w;
        double ph = (double)b * (double)l0;
        ph -= TWO_PI * rint(ph * INV_2PI);
        const float th = (float)ph;
        const float e0 = expf(a * (float)l0);
        float s0, c0;
        sincosf(th, &s0, &c0);
        float zr = e0 * c0;
        float zi = e0 * s0;
        const float eA = expf(a);
        float sb, cb;
        sincosf(b, &sb, &cb);
        const float str = eA * cb;
        const float sti = eA * sb;
        #pragma unroll
        for (int k = 0; k < CHUNK; ++k) {
            acc[k] = fmaf(wr, zr, fmaf(-wi, zi, acc[k]));
            const float nzr = zr * str - zi * sti;
            const float nzi = fmaf(zr, sti, zi * str);
            zr = nzr; zi = nzi;
        }
    }

    #pragma unroll
    for (int k = 0; k < CHUNK; ++k) {
        const int l = l0 + k;
        if (l < L) out[(size_t)l * H + h0 + hl] = acc[k];
    }
}

// ---------------- launch ----------------

extern "C" void kernel_launch(void* const* d_in, const int* in_sizes, int n_in,
                              void* d_out, int out_size, void* d_ws, size_t ws_size,
                              hipStream_t stream) {
    const float* log_dt = (const float*)d_in[0];
    const float* llnr   = (const float*)d_in[1];
    const float* lim    = (const float*)d_in[2];
    const float* W      = (const float*)d_in[3];
    const int*   Lp     = (const int*)d_in[4];

    const int H = in_sizes[0] / 2;
    const int N = in_sizes[1];
    const int L = out_size / (H > 0 ? H : 1);

    if (H == H_DIM && N == N_DIM && L <= 16 * BL) {
        const int lsegs = (L + BL - 1) / BL;
        dim3 grid(H_DIM / BH, lsegs);      // 64 x 16 = 1024 blocks = 4/CU
        dss_wloc<<<grid, 256, 0, stream>>>(log_dt, llnr, lim, W, Lp, (float*)d_out);
    } else {
        dim3 grid((H + HT - 1) / HT, (L + 63) / 64);
        dss_kernel_fb<<<grid, 256, 0, stream>>>(log_dt, llnr, lim, W, Lp,
                                                (float*)d_out, H, N);
    }
}

// Round 12
// 14.630 us; speedup vs baseline: 1.6089x; 1.6089x over previous
//
#include <hip/hip_runtime.h>
#include <math.h>

#define H_DIM 1024
#define N_DIM 64

typedef __attribute__((ext_vector_type(8))) _Float16 f16x8;
typedef __attribute__((ext_vector_type(4))) float f32x4;

__device__ __forceinline__ float2 cmul(float2 a, float2 b) {
    return make_float2(fmaf(a.x, b.x, -(a.y * b.y)),
                       fmaf(a.x, b.y,   a.y * b.x));
}

__device__ __forceinline__ unsigned pkh(float x, float y) {
    union { _Float16 h[2]; unsigned u; } p;
    p.h[0] = (_Float16)x; p.h[1] = (_Float16)y;
    return p.u;
}

// ---------------- MFMA path ----------------
// Block: 16 h x 256 l. Wave w owns h = h0+4w+j (j=0..3), lane = n.
// Per (h): A'[q][k], B'[r][k] fp16 pairs in LDS ([16 rows][64+4 pad] u32),
// 4x mfma_f32_16x16x32_f16 -> C[q][r] = out[256g+16q+r][h].

__global__ __launch_bounds__(256, 2) void dss_mfma(
    const float* __restrict__ log_dt,   // (H,2)
    const float* __restrict__ llnr,     // (N,)
    const float* __restrict__ limv,     // (N,)
    const float* __restrict__ W,        // (H,N,2)
    const int*   __restrict__ Lp,
    float* __restrict__ out)            // (L,H)
{
    __shared__ unsigned apb[4][2][16][68];   // 34816 B: per-wave A,B pair tables
    __shared__ float    scr[256][20];        // 20480 B: C tile [l][16h + pad]

    const int tid  = threadIdx.x;
    const int w    = tid >> 6;
    const int lane = tid & 63;               // = n
    const int h0   = blockIdx.x * 16;
    const int g    = blockIdx.y;             // 256-l segment (0..7)
    const int L    = *Lp;

    const int fr = lane & 15;                // frag row (q for A, r for B)
    const int kg = lane >> 4;                // frag k-group

    // lane <-> n constants
    const float lre = -expf(llnr[lane]);
    const float lmi = limv[lane];
    const float den = fmaxf(lre * lre + lmi * lmi, 1e-14f);
    const float rr = lre / den, ri = -lmi / den;

    unsigned* Atab = &apb[w][0][0][0];
    unsigned* Btab = &apb[w][1][0][0];

    #pragma unroll 1
    for (int j = 0; j < 4; ++j) {
        const int h = h0 + 4 * w + j;
        const float dt0 = expf(log_dt[2 * h]);
        const float dt1 = expf(log_dt[2 * h + 1]);
        const float a = dt0 * lre;
        const float b = dt1 * lmi;
        float sb, cbv;
        sincosf(b, &sb, &cbv);
        const float eA = expf(a);
        const float2 s = make_float2(eA * cbv, eA * sb);   // exp(dt_Lambda)

        // Wk = Wc * (exp(dtL)-1) * conj(Lam)/max(|Lam|^2,eps^2)
        const float2 wc = ((const float2*)W)[(size_t)h * N_DIM + lane];
        const float2 em1 = make_float2(s.x - 1.0f, s.y);
        const float2 t  = make_float2(em1.x * rr - em1.y * ri,
                                      em1.x * ri + em1.y * rr);
        const float2 wk = make_float2(wc.x * t.x - wc.y * t.y,
                                      wc.x * t.y + wc.y * t.x);

        // powers of s
        const float2 s2 = cmul(s, s), s4 = cmul(s2, s2), s8 = cmul(s4, s4);
        const float2 s12 = cmul(s8, s4), s16 = cmul(s8, s8);
        const float2 s32 = cmul(s16, s16), s64 = cmul(s32, s32);
        const float2 s128 = cmul(s64, s64), s192 = cmul(s128, s64);
        const float2 s256 = cmul(s128, s128);
        const float2 s512 = cmul(s256, s256), s1024 = cmul(s512, s512);

        float2 w0 = wk;                       // wk * s^(256g)
        if (g & 1) w0 = cmul(w0, s256);
        if (g & 2) w0 = cmul(w0, s512);
        if (g & 4) w0 = cmul(w0, s1024);

        // B chain: Bv[r] = s^r (4-way ILP)
        float2 Bv[16];
        Bv[0] = make_float2(1.0f, 0.0f); Bv[4] = s4; Bv[8] = s8; Bv[12] = s12;
        #pragma unroll
        for (int k = 1; k < 4; ++k) {
            Bv[k]      = cmul(Bv[k - 1], s);
            Bv[4 + k]  = cmul(Bv[4 + k - 1], s);
            Bv[8 + k]  = cmul(Bv[8 + k - 1], s);
            Bv[12 + k] = cmul(Bv[12 + k - 1], s);
        }
        // A chain: Av[q] = w0 * s16^q (4-way ILP)
        float2 Av[16];
        Av[0] = w0; Av[4] = cmul(w0, s64); Av[8] = cmul(w0, s128); Av[12] = cmul(w0, s192);
        #pragma unroll
        for (int k = 1; k < 4; ++k) {
            Av[k]      = cmul(Av[k - 1], s16);
            Av[4 + k]  = cmul(Av[4 + k - 1], s16);
            Av[8 + k]  = cmul(Av[8 + k - 1], s16);
            Av[12 + k] = cmul(Av[12 + k - 1], s16);
        }

        // pack fp16 pairs -> LDS: row stride 68 u32 (2-way banks max)
        #pragma unroll
        for (int q = 0; q < 16; ++q)
            Atab[q * 68 + lane] = pkh(Av[q].x, Av[q].y);       // (Re, Im)
        #pragma unroll
        for (int r = 0; r < 16; ++r)
            Btab[r * 68 + lane] = pkh(Bv[r].x, -Bv[r].y);      // (Re, -Im)

        // 4 MFMA K-calls (same-wave DS ordering; compiler inserts lgkmcnt)
        f32x4 acc = {0.0f, 0.0f, 0.0f, 0.0f};
        #pragma unroll
        for (int c = 0; c < 4; ++c) {
            const f16x8 af = *(const f16x8*)&Atab[fr * 68 + 16 * c + 4 * kg];
            const f16x8 bf = *(const f16x8*)&Btab[fr * 68 + 16 * c + 4 * kg];
            acc = __builtin_amdgcn_mfma_f32_16x16x32_f16(af, bf, acc, 0, 0, 0);
        }

        // C stage: lane holds C[q=4kg+reg][r=fr] -> l = 64kg + 16reg + fr
        const int hl  = 4 * w + j;
        const int col = hl ^ (kg << 2);      // quad-swap swizzle (bank spread)
        float* cbase = &scr[64 * kg + fr][col];
        #pragma unroll
        for (int reg = 0; reg < 4; ++reg)
            cbase[reg * (16 * 20)] = acc[reg];
    }

    __syncthreads();

    // epilogue: coalesced 64B rows [l][16h]
    const float4* scr4 = (const float4*)&scr[0][0];
    float4* out4 = (float4*)out;
    const int l0 = g * 256;
    #pragma unroll
    for (int i = 0; i < 4; ++i) {
        const int item = i * 256 + tid;      // 1024 = 256 l x 4 quads
        const int l = item >> 2, q = item & 3;
        const int gl = l0 + l;
        if (gl < L)
            out4[(size_t)gl * (H_DIM / 4) + (h0 >> 2) + q] =
                scr4[l * 5 + (q ^ (l >> 6))];
    }
}

// ---------------- generic fallback (round-1 proven structure) ----------------

#define HT 64
#define CHUNK 16

__global__ __launch_bounds__(256) void dss_kernel_fb(
    const float* __restrict__ log_dt,
    const float* __restrict__ lam_log_neg_re,
    const float* __restrict__ lam_im,
    const float* __restrict__ W,
    const int*   __restrict__ Lp,
    float* __restrict__ out,
    int H, int N)
{
    __shared__ float4 params[N_DIM * HT];
    const int tid = threadIdx.x;
    const int h0 = blockIdx.x * HT;
    const int l0_blk = blockIdx.y * 64;
    const int L = *Lp;
    const float2* __restrict__ W2 = (const float2*)W;

    for (int flat = tid; flat < N * HT; flat += 256) {
        const int hl = flat & (HT - 1);
        const int n  = flat >> 6;
        const int h  = h0 + hl;
        const float dt0 = expf(log_dt[2 * h]);
        const float dt1 = expf(log_dt[2 * h + 1]);
        const float lre = -expf(lam_log_neg_re[n]);
        const float lmi = lam_im[n];
        const float a = dt0 * lre;
        const float b = dt1 * lmi;
        const float eA = expf(a);
        float sb, cb;
        sincosf(b, &sb, &cb);
        const float em1r = eA * cb - 1.0f;
        const float em1i = eA * sb;
        const float den = fmaxf(lre * lre + lmi * lmi, 1e-14f);
        const float rr =  lre / den;
        const float ri = -lmi / den;
        const float2 wc = W2[h * N + n];
        const float trm = em1r * rr - em1i * ri;
        const float tim = em1r * ri + em1i * rr;
        params[flat] = make_float4(a, b,
                                   wc.x * trm - wc.y * tim,
                                   wc.x * tim + wc.y * trm);
    }
    __syncthreads();

    const int hl = tid & (HT - 1);
    const int chunk = tid >> 6;
    const int l0 = l0_blk + chunk * CHUNK;
    if (l0 >= L) return;

    float acc[CHUNK];
    #pragma unroll
    for (int k = 0; k < CHUNK; ++k) acc[k] = 0.0f;

    const double TWO_PI  = 6.283185307179586476925286766559;
    const double INV_2PI = 0.15915494309189533576888376337251;

    for (int n = 0; n < N; ++n) {
        const float4 pp = params[n * HT + hl];
        const float a = pp.x, b = pp.y, wr = pp.z, wi = pp.w;
        double ph = (double)b * (double)l0;
        ph -= TWO_PI * rint(ph * INV_2PI);
        const float th = (float)ph;
        const float e0 = expf(a * (float)l0);
        float s0, c0;
        sincosf(th, &s0, &c0);
        float zr = e0 * c0;
        float zi = e0 * s0;
        const float eA = expf(a);
        float sb, cb;
        sincosf(b, &sb, &cb);
        const float str = eA * cb;
        const float sti = eA * sb;
        #pragma unroll
        for (int k = 0; k < CHUNK; ++k) {
            acc[k] = fmaf(wr, zr, fmaf(-wi, zi, acc[k]));
            const float nzr = zr * str - zi * sti;
            const float nzi = fmaf(zr, sti, zi * str);
            zr = nzr; zi = nzi;
        }
    }

    #pragma unroll
    for (int k = 0; k < CHUNK; ++k) {
        const int l = l0 + k;
        if (l < L) out[(size_t)l * H + h0 + hl] = acc[k];
    }
}

// ---------------- launch ----------------

extern "C" void kernel_launch(void* const* d_in, const int* in_sizes, int n_in,
                              void* d_out, int out_size, void* d_ws, size_t ws_size,
                              hipStream_t stream) {
    const float* log_dt = (const float*)d_in[0];
    const float* llnr   = (const float*)d_in[1];
    const float* lim    = (const float*)d_in[2];
    const float* W      = (const float*)d_in[3];
    const int*   Lp     = (const int*)d_in[4];

    const int H = in_sizes[0] / 2;
    const int N = in_sizes[1];
    const int L = out_size / (H > 0 ? H : 1);

    if (H == H_DIM && N == N_DIM && L <= 2048) {
        dim3 grid(H_DIM / 16, (L + 255) / 256);   // 64 x 8 = 512 blocks
        dss_mfma<<<grid, 256, 0, stream>>>(log_dt, llnr, lim, W, Lp, (float*)d_out);
    } else {
        dim3 grid((H + HT - 1) / HT, (L + 63) / 64);
        dss_kernel_fb<<<grid, 256, 0, stream>>>(log_dt, llnr, lim, W, Lp,
                                                (float*)d_out, H, N);
    }
}

// Round 13
// 13.050 us; speedup vs baseline: 1.8037x; 1.1210x over previous
//
#include <hip/hip_runtime.h>
#include <math.h>

#define H_DIM 1024
#define N_DIM 64

typedef __attribute__((ext_vector_type(8))) _Float16 f16x8;
typedef __attribute__((ext_vector_type(4))) float f32x4;

__device__ __forceinline__ float2 cmul(float2 a, float2 b) {
    return make_float2(fmaf(a.x, b.x, -(a.y * b.y)),
                       fmaf(a.x, b.y,   a.y * b.x));
}

__device__ __forceinline__ unsigned pkh(float x, float y) {
    union { _Float16 h[2]; unsigned u; } p;
    p.h[0] = (_Float16)x; p.h[1] = (_Float16)y;
    return p.u;
}

// ---------------- MFMA path (round-13: 8h blocks, 4/CU, native trig) ----------------
// Block: 8 h x 256 l, 4 waves; wave owns h = h0 + 2w + j (j=0..1), lane = n.
// Per (h): A'[q][k], B'[r][k] fp16 pairs in LDS ([16 rows][68 pad] u32),
// 4x mfma_f32_16x16x32_f16 -> C[q][r] = out[256g+16q+r][h]. C held in regs;
// epilogue stages C into LDS *aliased over the tables* (union) -> 34.8 KB.

__global__ __launch_bounds__(256, 4) void dss_mfma2(
    const float* __restrict__ log_dt,   // (H,2)
    const float* __restrict__ llnr,     // (N,)
    const float* __restrict__ limv,     // (N,)
    const float* __restrict__ W,        // (H,N,2)
    const int*   __restrict__ Lp,
    float* __restrict__ out)            // (L,H)
{
    __shared__ unsigned lds_raw[4 * 2 * 16 * 68];   // 34816 B (tables / scr union)

    const int tid  = threadIdx.x;
    const int w    = tid >> 6;
    const int lane = tid & 63;               // = n

    // XCD-aware block swizzle: 4 consecutive h-tiles + same g -> same XCD
    int htile, g;
    if (gridDim.y == 8 && gridDim.x == 128) {
        const int id = blockIdx.x + (blockIdx.y << 7);
        g = id & 7;
        const int q = id >> 3;               // 0..127
        htile = 4 * (q & 31) + (q >> 5);
    } else { htile = blockIdx.x; g = blockIdx.y; }

    const int h0 = htile * 8;
    const int L  = *Lp;
    const int fr = lane & 15;                // frag row (q for A, r for B)
    const int kg = lane >> 4;                // frag k-group

    // lane <-> n constants
    const float lre = -__expf(llnr[lane]);
    const float lmi = limv[lane];
    const float den = fmaxf(fmaf(lre, lre, lmi * lmi), 1e-14f);
    const float rde = __builtin_amdgcn_rcpf(den);
    const float rr = lre * rde, ri = -lmi * rde;

    unsigned* Atab = lds_raw + w * (2 * 16 * 68);
    unsigned* Btab = Atab + 16 * 68;

    f32x4 accs[2];

    #pragma unroll
    for (int j = 0; j < 2; ++j) {
        const int h = h0 + 2 * w + j;
        const float dt0 = __expf(log_dt[2 * h]);
        const float dt1 = __expf(log_dt[2 * h + 1]);
        const float a = dt0 * lre;
        const float b = dt1 * lmi;
        const float eA = __expf(a);
        const float sb = __sinf(b), cbv = __cosf(b);
        const float2 s = make_float2(eA * cbv, eA * sb);   // exp(dt_Lambda)

        // Wk = Wc * (exp(dtL)-1) * conj(Lam)/max(|Lam|^2,eps^2)
        const float2 wc = ((const float2*)W)[(size_t)h * N_DIM + lane];
        const float2 em1 = make_float2(s.x - 1.0f, s.y);
        const float2 t  = make_float2(em1.x * rr - em1.y * ri,
                                      em1.x * ri + em1.y * rr);
        const float2 wk = make_float2(wc.x * t.x - wc.y * t.y,
                                      wc.x * t.y + wc.y * t.x);

        // powers of s
        const float2 s2 = cmul(s, s), s4 = cmul(s2, s2), s8 = cmul(s4, s4);
        const float2 s12 = cmul(s8, s4), s16 = cmul(s8, s8);
        const float2 s32 = cmul(s16, s16), s64 = cmul(s32, s32);
        const float2 s128 = cmul(s64, s64), s192 = cmul(s128, s64);
        const float2 s256 = cmul(s128, s128);
        const float2 s512 = cmul(s256, s256), s1024 = cmul(s512, s512);

        float2 w0 = wk;                       // wk * s^(256g)
        if (g & 1) w0 = cmul(w0, s256);
        if (g & 2) w0 = cmul(w0, s512);
        if (g & 4) w0 = cmul(w0, s1024);

        // B chain: Bv[r] = s^r (4-way ILP)
        float2 Bv[16];
        Bv[0] = make_float2(1.0f, 0.0f); Bv[4] = s4; Bv[8] = s8; Bv[12] = s12;
        #pragma unroll
        for (int k = 1; k < 4; ++k) {
            Bv[k]      = cmul(Bv[k - 1], s);
            Bv[4 + k]  = cmul(Bv[4 + k - 1], s);
            Bv[8 + k]  = cmul(Bv[8 + k - 1], s);
            Bv[12 + k] = cmul(Bv[12 + k - 1], s);
        }
        // A chain: Av[q] = w0 * s16^q (4-way ILP)
        float2 Av[16];
        Av[0] = w0; Av[4] = cmul(w0, s64); Av[8] = cmul(w0, s128); Av[12] = cmul(w0, s192);
        #pragma unroll
        for (int k = 1; k < 4; ++k) {
            Av[k]      = cmul(Av[k - 1], s16);
            Av[4 + k]  = cmul(Av[4 + k - 1], s16);
            Av[8 + k]  = cmul(Av[8 + k - 1], s16);
            Av[12 + k] = cmul(Av[12 + k - 1], s16);
        }

        // pack fp16 pairs -> LDS: row stride 68 u32 (2-way banks max)
        #pragma unroll
        for (int q = 0; q < 16; ++q)
            Atab[q * 68 + lane] = pkh(Av[q].x, Av[q].y);       // (Re, Im)
        #pragma unroll
        for (int r = 0; r < 16; ++r)
            Btab[r * 68 + lane] = pkh(Bv[r].x, -Bv[r].y);      // (Re, -Im)

        // 4 MFMA K-calls (same-wave DS ordering; compiler inserts lgkmcnt)
        f32x4 acc = {0.0f, 0.0f, 0.0f, 0.0f};
        #pragma unroll
        for (int c = 0; c < 4; ++c) {
            const f16x8 af = *(const f16x8*)&Atab[fr * 68 + 16 * c + 4 * kg];
            const f16x8 bf = *(const f16x8*)&Btab[fr * 68 + 16 * c + 4 * kg];
            acc = __builtin_amdgcn_mfma_f32_16x16x32_f16(af, bf, acc, 0, 0, 0);
        }
        accs[j] = acc;
    }

    // ---- epilogue: C regs -> LDS (aliased over tables) -> coalesced stores ----
    __syncthreads();                         // all waves done reading tables
    float* scr = (float*)lds_raw;            // [256 l][12 floats: 8 h + pad]
    #pragma unroll
    for (int j = 0; j < 2; ++j) {
        const int hl = 2 * w + j;
        #pragma unroll
        for (int reg = 0; reg < 4; ++reg)
            scr[(64 * kg + 16 * reg + fr) * 12 + hl] = accs[j][reg];
    }
    __syncthreads();

    const float4* scr4 = (const float4*)scr;
    float4* out4 = (float4*)out;
    const int l0 = g * 256;
    #pragma unroll
    for (int i = 0; i < 2; ++i) {
        const int flat = i * 256 + tid;      // 512 = 256 l x 2 quads
        const int l = flat >> 1, q = flat & 1;
        const int gl = l0 + l;
        if (gl < L)
            out4[(size_t)gl * (H_DIM / 4) + htile * 2 + q] = scr4[l * 3 + q];
    }
}

// ---------------- generic fallback (round-1 proven structure) ----------------

#define HT 64
#define CHUNK 16

__global__ __launch_bounds__(256) void dss_kernel_fb(
    const float* __restrict__ log_dt,
    const float* __restrict__ lam_log_neg_re,
    const float* __restrict__ lam_im,
    const float* __restrict__ W,
    const int*   __restrict__ Lp,
    float* __restrict__ out,
    int H, int N)
{
    __shared__ float4 params[N_DIM * HT];
    const int tid = threadIdx.x;
    const int h0 = blockIdx.x * HT;
    const int l0_blk = blockIdx.y * 64;
    const int L = *Lp;
    const float2* __restrict__ W2 = (const float2*)W;

    for (int flat = tid; flat < N * HT; flat += 256) {
        const int hl = flat & (HT - 1);
        const int n  = flat >> 6;
        const int h  = h0 + hl;
        const float dt0 = expf(log_dt[2 * h]);
        const float dt1 = expf(log_dt[2 * h + 1]);
        const float lre = -expf(lam_log_neg_re[n]);
        const float lmi = lam_im[n];
        const float a = dt0 * lre;
        const float b = dt1 * lmi;
        const float eA = expf(a);
        float sb, cb;
        sincosf(b, &sb, &cb);
        const float em1r = eA * cb - 1.0f;
        const float em1i = eA * sb;
        const float den = fmaxf(lre * lre + lmi * lmi, 1e-14f);
        const float rr =  lre / den;
        const float ri = -lmi / den;
        const float2 wc = W2[h * N + n];
        const float trm = em1r * rr - em1i * ri;
        const float tim = em1r * ri + em1i * rr;
        params[flat] = make_float4(a, b,
                                   wc.x * trm - wc.y * tim,
                                   wc.x * tim + wc.y * trm);
    }
    __syncthreads();

    const int hl = tid & (HT - 1);
    const int chunk = tid >> 6;
    const int l0 = l0_blk + chunk * CHUNK;
    if (l0 >= L) return;

    float acc[CHUNK];
    #pragma unroll
    for (int k = 0; k < CHUNK; ++k) acc[k] = 0.0f;

    const double TWO_PI  = 6.283185307179586476925286766559;
    const double INV_2PI = 0.15915494309189533576888376337251;

    for (int n = 0; n < N; ++n) {
        const float4 pp = params[n * HT + hl];
        const float a = pp.x, b = pp.y, wr = pp.z, wi = pp.w;
        double ph = (double)b * (double)l0;
        ph -= TWO_PI * rint(ph * INV_2PI);
        const float th = (float)ph;
        const float e0 = expf(a * (float)l0);
        float s0, c0;
        sincosf(th, &s0, &c0);
        float zr = e0 * c0;
        float zi = e0 * s0;
        const float eA = expf(a);
        float sb, cb;
        sincosf(b, &sb, &cb);
        const float str = eA * cb;
        const float sti = eA * sb;
        #pragma unroll
        for (int k = 0; k < CHUNK; ++k) {
            acc[k] = fmaf(wr, zr, fmaf(-wi, zi, acc[k]));
            const float nzr = zr * str - zi * sti;
            const float nzi = fmaf(zr, sti, zi * str);
            zr = nzr; zi = nzi;
        }
    }

    #pragma unroll
    for (int k = 0; k < CHUNK; ++k) {
        const int l = l0 + k;
        if (l < L) out[(size_t)l * H + h0 + hl] = acc[k];
    }
}

// ---------------- launch ----------------

extern "C" void kernel_launch(void* const* d_in, const int* in_sizes, int n_in,
                              void* d_out, int out_size, void* d_ws, size_t ws_size,
                              hipStream_t stream) {
    const float* log_dt = (const float*)d_in[0];
    const float* llnr   = (const float*)d_in[1];
    const float* lim    = (const float*)d_in[2];
    const float* W      = (const float*)d_in[3];
    const int*   Lp     = (const int*)d_in[4];

    const int H = in_sizes[0] / 2;
    const int N = in_sizes[1];
    const int L = out_size / (H > 0 ? H : 1);

    if (H == H_DIM && N == N_DIM && L <= 2048) {
        dim3 grid(H_DIM / 8, (L + 255) / 256);   // 128 x 8 = 1024 blocks = 4/CU
        dss_mfma2<<<grid, 256, 0, stream>>>(log_dt, llnr, lim, W, Lp, (float*)d_out);
    } else {
        dim3 grid((H + HT - 1) / HT, (L + 63) / 64);
        dss_kernel_fb<<<grid, 256, 0, stream>>>(log_dt, llnr, lim, W, Lp,
                                                (float*)d_out, H, N);
    }
}

// Round 14
// 12.067 us; speedup vs baseline: 1.9506x; 1.0814x over previous
//
#include <hip/hip_runtime.h>
#include <math.h>

#define H_DIM 1024
#define N_DIM 64

typedef __attribute__((ext_vector_type(8))) _Float16 f16x8;
typedef __attribute__((ext_vector_type(16))) float f32x16;

__device__ __forceinline__ float2 cmul(float2 a, float2 b) {
    return make_float2(fmaf(a.x, b.x, -(a.y * b.y)),
                       fmaf(a.x, b.y,   a.y * b.x));
}

__device__ __forceinline__ unsigned pkh(float x, float y) {
    union { _Float16 h[2]; unsigned u; } p;
    p.h[0] = (_Float16)x; p.h[1] = (_Float16)y;
    return p.u;
}

// ---------------- 32x32 MFMA path ----------------
// Block: 4 h x 1024 l (4 waves; wave w owns h = 4*htile + w, lane = n).
// l - l0 = 32q + r. A[q] = wk*s^l0*s32^q, B[r] = s^r: 64 table rows ->
// 8x mfma_f32_32x32x16_f16 -> C[q][r]. Tables: [row][n^((row&7)<<2)] u32,
// stride 64 (XOR-swizzled, no pad) -> 16 KB/wave, 64 KB/block, 2 blocks/CU.

__global__ __launch_bounds__(256, 2) void dss_mfma32(
    const float* __restrict__ log_dt,   // (H,2)
    const float* __restrict__ llnr,     // (N,)
    const float* __restrict__ limv,     // (N,)
    const float* __restrict__ W,        // (H,N,2)
    const int*   __restrict__ Lp,
    float* __restrict__ out)            // (L,H)
{
    __shared__ unsigned lds_raw[4 * 2 * 32 * 64];   // 65536 B

    const int tid  = threadIdx.x;
    const int w    = tid >> 6;
    const int lane = tid & 63;               // = n

    // XCD swizzle: each XCD gets a contiguous 32-htile (128 h) span, same half.
    const int raw = blockIdx.x + (blockIdx.y << 8);   // grid (256, halves)
    const int r7 = raw & 7, q9 = raw >> 3;
    const int half  = q9 >> 5;
    const int htile = (r7 << 5) | (q9 & 31);          // bijective for 256 tiles

    const int L  = *Lp;
    const int l0 = half << 10;
    if (l0 >= L) return;                     // block-uniform, pre-barrier

    const int h = htile * 4 + w;

    unsigned* Atab = lds_raw + w * (2 * 32 * 64);
    unsigned* Btab = Atab + 32 * 64;

    // swizzled lane columns: lx[m] = lane ^ (m<<2)
    int lx[8];
    #pragma unroll
    for (int m = 0; m < 8; ++m) lx[m] = lane ^ (m << 2);

    // lane <-> n constants
    const float lre = -__expf(llnr[lane]);
    const float lmi = limv[lane];
    const float den = fmaxf(fmaf(lre, lre, lmi * lmi), 1e-14f);
    const float rde = __builtin_amdgcn_rcpf(den);
    const float rr = lre * rde, ri = -lmi * rde;

    // per-(h,n) scalars
    const float dt0 = __expf(log_dt[2 * h]);
    const float dt1 = __expf(log_dt[2 * h + 1]);
    const float a = dt0 * lre;
    const float b = dt1 * lmi;
    const float eA = __expf(a);
    const float snb = __sinf(b), csb = __cosf(b);
    const float2 s = make_float2(eA * csb, eA * snb);   // exp(dt_Lambda)

    // Wk = Wc * (exp(dtL)-1) * conj(Lam)/max(|Lam|^2,eps^2)
    const float2 wc = ((const float2*)W)[(size_t)h * N_DIM + lane];
    const float2 em1 = make_float2(s.x - 1.0f, s.y);
    const float2 t  = make_float2(em1.x * rr - em1.y * ri,
                                  em1.x * ri + em1.y * rr);
    const float2 wk = make_float2(wc.x * t.x - wc.y * t.y,
                                  wc.x * t.y + wc.y * t.x);

    // powers of s
    const float2 s2 = cmul(s, s), s4 = cmul(s2, s2), s8 = cmul(s4, s4);
    const float2 s16 = cmul(s8, s8), s24 = cmul(s16, s8);
    const float2 s32 = cmul(s16, s16), s64 = cmul(s32, s32);
    const float2 s128 = cmul(s64, s64), s256 = cmul(s128, s128);
    const float2 s512 = cmul(s256, s256), s768 = cmul(s512, s256);
    const float2 s1024 = cmul(s512, s512);

    const float2 w0 = half ? cmul(wk, s1024) : wk;      // wk * s^l0

    // B rows r=0..31: s^r packed (Re, -Im); 4-way ILP chains
    {
        float2 v0 = make_float2(1.0f, 0.0f), v1 = s8, v2 = s16, v3 = s24;
        Btab[ 0 * 64 + lx[0]] = pkh(v0.x, -v0.y);
        Btab[ 8 * 64 + lx[0]] = pkh(v1.x, -v1.y);
        Btab[16 * 64 + lx[0]] = pkh(v2.x, -v2.y);
        Btab[24 * 64 + lx[0]] = pkh(v3.x, -v3.y);
        #pragma unroll
        for (int k = 1; k < 8; ++k) {
            v0 = cmul(v0, s); v1 = cmul(v1, s);
            v2 = cmul(v2, s); v3 = cmul(v3, s);
            Btab[( 0 + k) * 64 + lx[k]] = pkh(v0.x, -v0.y);
            Btab[( 8 + k) * 64 + lx[k]] = pkh(v1.x, -v1.y);
            Btab[(16 + k) * 64 + lx[k]] = pkh(v2.x, -v2.y);
            Btab[(24 + k) * 64 + lx[k]] = pkh(v3.x, -v3.y);
        }
    }
    // A rows q=0..31: w0*s32^q packed (Re, Im); 4-way ILP chains
    {
        float2 v0 = w0, v1 = cmul(w0, s256), v2 = cmul(w0, s512), v3 = cmul(w0, s768);
        Atab[ 0 * 64 + lx[0]] = pkh(v0.x, v0.y);
        Atab[ 8 * 64 + lx[0]] = pkh(v1.x, v1.y);
        Atab[16 * 64 + lx[0]] = pkh(v2.x, v2.y);
        Atab[24 * 64 + lx[0]] = pkh(v3.x, v3.y);
        #pragma unroll
        for (int k = 1; k < 8; ++k) {
            v0 = cmul(v0, s32); v1 = cmul(v1, s32);
            v2 = cmul(v2, s32); v3 = cmul(v3, s32);
            Atab[( 0 + k) * 64 + lx[k]] = pkh(v0.x, v0.y);
            Atab[( 8 + k) * 64 + lx[k]] = pkh(v1.x, v1.y);
            Atab[(16 + k) * 64 + lx[k]] = pkh(v2.x, v2.y);
            Atab[(24 + k) * 64 + lx[k]] = pkh(v3.x, v3.y);
        }
    }

    // 8 MFMA calls over n (same-wave DS ordering; compiler inserts lgkmcnt)
    const int row = lane & 31;
    const int hi  = lane >> 5;
    const unsigned rsw = (unsigned)((row & 7) << 2);
    const unsigned* Arow = Atab + row * 64;
    const unsigned* Brow = Btab + row * 64;
    f32x16 acc = {0.0f, 0.0f, 0.0f, 0.0f, 0.0f, 0.0f, 0.0f, 0.0f,
                  0.0f, 0.0f, 0.0f, 0.0f, 0.0f, 0.0f, 0.0f, 0.0f};
    #pragma unroll
    for (int c = 0; c < 8; ++c) {
        const unsigned off = (unsigned)(8 * c + 4 * hi) ^ rsw;
        const f16x8 af = *(const f16x8*)&Arow[off];
        const f16x8 bf = *(const f16x8*)&Brow[off];
        acc = __builtin_amdgcn_mfma_f32_32x32x16_f16(af, bf, acc, 0, 0, 0);
    }

    // ---- C stage: regs -> LDS [1024 l][5] (aliased over tables) ----
    __syncthreads();                         // all waves done with tables
    float* scr = (float*)lds_raw;            // 1024 x 5 floats = 20480 B
    const int r32 = lane & 31;
    #pragma unroll
    for (int reg = 0; reg < 16; ++reg) {
        const int q = (reg & 3) + 8 * (reg >> 2) + 4 * hi;
        scr[(32 * q + r32) * 5 + w] = acc[reg];
    }
    __syncthreads();

    // ---- epilogue: float4 stores (16 B per l; XCD-contiguous h spans) ----
    float4* out4 = (float4*)out;
    #pragma unroll
    for (int i = 0; i < 4; ++i) {
        const int l = i * 256 + tid;
        const int gl = l0 + l;
        if (gl < L) {
            const float* p = &scr[l * 5];
            out4[(size_t)gl * (H_DIM / 4) + htile] =
                make_float4(p[0], p[1], p[2], p[3]);
        }
    }
}

// ---------------- generic fallback (round-1 proven structure) ----------------

#define HT 64
#define CHUNK 16

__global__ __launch_bounds__(256) void dss_kernel_fb(
    const float* __restrict__ log_dt,
    const float* __restrict__ lam_log_neg_re,
    const float* __restrict__ lam_im,
    const float* __restrict__ W,
    const int*   __restrict__ Lp,
    float* __restrict__ out,
    int H, int N)
{
    __shared__ float4 params[N_DIM * HT];
    const int tid = threadIdx.x;
    const int h0 = blockIdx.x * HT;
    const int l0_blk = blockIdx.y * 64;
    const int L = *Lp;
    const float2* __restrict__ W2 = (const float2*)W;

    for (int flat = tid; flat < N * HT; flat += 256) {
        const int hl = flat & (HT - 1);
        const int n  = flat >> 6;
        const int h  = h0 + hl;
        const float dt0 = expf(log_dt[2 * h]);
        const float dt1 = expf(log_dt[2 * h + 1]);
        const float lre = -expf(lam_log_neg_re[n]);
        const float lmi = lam_im[n];
        const float a = dt0 * lre;
        const float b = dt1 * lmi;
        const float eA = expf(a);
        float sb, cb;
        sincosf(b, &sb, &cb);
        const float em1r = eA * cb - 1.0f;
        const float em1i = eA * sb;
        const float den = fmaxf(lre * lre + lmi * lmi, 1e-14f);
        const float rr =  lre / den;
        const float ri = -lmi / den;
        const float2 wc = W2[h * N + n];
        const float trm = em1r * rr - em1i * ri;
        const float tim = em1r * ri + em1i * rr;
        params[flat] = make_float4(a, b,
                                   wc.x * trm - wc.y * tim,
                                   wc.x * tim + wc.y * trm);
    }
    __syncthreads();

    const int hl = tid & (HT - 1);
    const int chunk = tid >> 6;
    const int l0 = l0_blk + chunk * CHUNK;
    if (l0 >= L) return;

    float acc[CHUNK];
    #pragma unroll
    for (int k = 0; k < CHUNK; ++k) acc[k] = 0.0f;

    const double TWO_PI  = 6.283185307179586476925286766559;
    const double INV_2PI = 0.15915494309189533576888376337251;

    for (int n = 0; n < N; ++n) {
        const float4 pp = params[n * HT + hl];
        const float a = pp.x, b = pp.y, wr = pp.z, wi = pp.w;
        double ph = (double)b * (double)l0;
        ph -= TWO_PI * rint(ph * INV_2PI);
        const float th = (float)ph;
        const float e0 = expf(a * (float)l0);
        float s0, c0;
        sincosf(th, &s0, &c0);
        float zr = e0 * c0;
        float zi = e0 * s0;
        const float eA = expf(a);
        float sb, cb;
        sincosf(b, &sb, &cb);
        const float str = eA * cb;
        const float sti = eA * sb;
        #pragma unroll
        for (int k = 0; k < CHUNK; ++k) {
            acc[k] = fmaf(wr, zr, fmaf(-wi, zi, acc[k]));
            const float nzr = zr * str - zi * sti;
            const float nzi = fmaf(zr, sti, zi * str);
            zr = nzr; zi = nzi;
        }
    }

    #pragma unroll
    for (int k = 0; k < CHUNK; ++k) {
        const int l = l0 + k;
        if (l < L) out[(size_t)l * H + h0 + hl] = acc[k];
    }
}

// ---------------- launch ----------------

extern "C" void kernel_launch(void* const* d_in, const int* in_sizes, int n_in,
                              void* d_out, int out_size, void* d_ws, size_t ws_size,
                              hipStream_t stream) {
    const float* log_dt = (const float*)d_in[0];
    const float* llnr   = (const float*)d_in[1];
    const float* lim    = (const float*)d_in[2];
    const float* W      = (const float*)d_in[3];
    const int*   Lp     = (const int*)d_in[4];

    const int H = in_sizes[0] / 2;
    const int N = in_sizes[1];
    const int L = out_size / (H > 0 ? H : 1);

    if (H == H_DIM && N == N_DIM && L <= 2048) {
        const int halves = (L + 1023) / 1024;
        dim3 grid(H_DIM / 4, halves);            // 256 x 2 = 512 blocks
        dss_mfma32<<<grid, 256, 0, stream>>>(log_dt, llnr, lim, W, Lp, (float*)d_out);
    } else {
        dim3 grid((H + HT - 1) / HT, (L + 63) / 64);
        dss_kernel_fb<<<grid, 256, 0, stream>>>(log_dt, llnr, lim, W, Lp,
                                                (float*)d_out, H, N);
    }
}